// Round 1
// baseline (165.489 us; speedup 1.0000x reference)
//
#include <hip/hip_runtime.h>
#include <cstddef>

// Voxel encoder: B=2, N=16384, G=512 voxels x K=32 pts, d=128, S=2 layers.
// Round 14: LDS diet -> 3 blocks/CU (was 2). Counters showed latency-bound
// (MfmaUtil 10%, VALU 35%, HBM 7%, Occ 33%) with LDS=64000B capping
// residency. Cuts: (1) f1_s eliminated -- layer-0 PV overwrites feats_s;
// the trans chunk consuming original feats is folded into layer 0 using the
// live avu regs (persistent tacc, +8 VGPR); (2) P moved into dead k-region
// cols 128..159, qk_s stride 440->424 (212 dw = 20 mod 32, 2-way-free);
// (3) red_s/wmax_s/pooled_s alias sc_s (dead after last softmax).
// New LDS = 50,816B. RULE (r8/r10): never force min-waves>2.

#define D_   128
#define VSF  0.25f
#define QSF  0.01f
#define LQ   50
#define G_   512
#define KP   32
#define BB   2
#define NP   16384
#define MT   32768
#define SCALE 0.08838834764831845f   // 1/sqrt(128)
#define NT_ALL 34           // 24 qkv tiles + 10 dk tiles (cols 0..543)
#define FRAG_S (NT_ALL * 4 * 64 * 8)   // ushorts per layer frag buffer

using short8 = __attribute__((ext_vector_type(8))) short;
using f32x4  = __attribute__((ext_vector_type(4))) float;

__device__ inline unsigned short f2bf(float x) {
  unsigned u = __builtin_bit_cast(unsigned, x);
  u += 0x7fffu + ((u >> 16) & 1u);      // round-to-nearest-even
  return (unsigned short)(u >> 16);
}
__device__ inline float bu(unsigned short h) {
  return __builtin_bit_cast(float, (unsigned)h << 16);
}
__device__ inline short8 as_short8(uint4 v) {
  union { uint4 u; short8 s; } x; x.u = v; return x.s;
}

// ---------------------------------------------------------------------------
// Transpose the (s,1) table slices into Tt[s][e=128][c=256], c = axis*50+l,
// zero-padded for c in [150,256). grid = 256 (s*128+e), block = 256 (c).
// ---------------------------------------------------------------------------
__global__ __launch_bounds__(256) void prep_tt(
    const float* __restrict__ tbl_x, const float* __restrict__ tbl_y,
    const float* __restrict__ tbl_z, float* __restrict__ Tt)
{
  const int c = threadIdx.x;
  const int s = blockIdx.x >> 7;
  const int e = blockIdx.x & 127;
  float v = 0.f;
  if (c < 150) {
    const int axis = c / 50, l = c - axis * 50;
    const float* tb = (axis == 0 ? tbl_x : (axis == 1 ? tbl_y : tbl_z));
    v = tb[(((size_t)s * 3 + 1) * LQ + l) * D_ + e];
  }
  Tt[((size_t)(s * 128 + e)) * 256 + c] = v;
}

// ---------------------------------------------------------------------------
// Wf = Wk @ Tt (fp32, both layers). grid=(2,2,2): x=m-tile, y=n-tile, z=s.
// ---------------------------------------------------------------------------
__global__ __launch_bounds__(256) void wf_gemm(
    const float* __restrict__ qkv_w, const float* __restrict__ Tt,
    float* __restrict__ Wf)
{
  __shared__ __align__(16) float A_s[16][68];
  __shared__ __align__(16) float B_s[16][132];
  const int t  = threadIdx.x;
  const int s  = blockIdx.z;
  const float* A = qkv_w + (size_t)s * 128 * 384 + 128;   // Wk rows, lda=384
  const float* B = Tt + (size_t)s * 128 * 256;
  float* C       = Wf + (size_t)s * 128 * 256;
  const int m0 = blockIdx.x * 64;
  const int n0 = blockIdx.y * 128;
  const int r  = t >> 2;
  const int kq = (t & 3) * 4;
  const float* arow = A + (size_t)(m0 + r) * 384;
  const int kkb = t >> 4;
  const int cb  = (t & 15) * 8;
  const float* wbase = B + (size_t)kkb * 256 + n0 + cb;
  const int tx = t & 31, ty = t >> 5;

  float acc[8][4];
  #pragma unroll
  for (int i = 0; i < 8; i++)
    #pragma unroll
    for (int j = 0; j < 4; j++) acc[i][j] = 0.f;

  for (int k0 = 0; k0 < 128; k0 += 16) {
    float4 av = *(const float4*)(arow + k0 + kq);
    float4 b0 = *(const float4*)(wbase + (size_t)k0 * 256);
    float4 b1 = *(const float4*)(wbase + (size_t)k0 * 256 + 4);
    __syncthreads();
    A_s[kq + 0][r] = av.x;
    A_s[kq + 1][r] = av.y;
    A_s[kq + 2][r] = av.z;
    A_s[kq + 3][r] = av.w;
    *(float4*)&B_s[kkb][cb]     = b0;
    *(float4*)&B_s[kkb][cb + 4] = b1;
    __syncthreads();
    #pragma unroll
    for (int kk = 0; kk < 16; kk++) {
      float4 a03 = *(const float4*)&A_s[kk][ty * 8];
      float4 a47 = *(const float4*)&A_s[kk][ty * 8 + 4];
      float4 bv  = *(const float4*)&B_s[kk][tx * 4];
      float a[8] = {a03.x, a03.y, a03.z, a03.w, a47.x, a47.y, a47.z, a47.w};
      float bj[4] = {bv.x, bv.y, bv.z, bv.w};
      #pragma unroll
      for (int i = 0; i < 8; i++)
        #pragma unroll
        for (int j = 0; j < 4; j++)
          acc[i][j] += a[i] * bj[j];
    }
  }
  #pragma unroll
  for (int i = 0; i < 8; i++) {
    float4 o = {acc[i][0], acc[i][1], acc[i][2], acc[i][3]};
    *(float4*)(C + (size_t)(m0 + ty * 8 + i) * 256 + n0 + tx * 4) = o;
  }
}

// ---------------------------------------------------------------------------
// pack2: all fragment packing + combined bias in one launch. 370 blocks x 64.
// ---------------------------------------------------------------------------
__global__ __launch_bounds__(64) void pack2(
    const float* __restrict__ qkv_w, const float* __restrict__ Wf,
    const float* __restrict__ trans_w, const float* __restrict__ qkv_b,
    const float* __restrict__ Tt,
    unsigned short* __restrict__ allfrag,
    unsigned short* __restrict__ transfrag,
    float* __restrict__ bc)
{
  const int blk = blockIdx.x;
  const int lane = threadIdx.x;
  const float* B; int ldb, dstidx; unsigned short* dst; int kbase, n;
  if (blk < 192) {
    const int s = blk / 96, r = blk - s * 96;
    const int nt = r >> 2, ks = r & 3;
    B = qkv_w + (size_t)s * 128 * 384; ldb = 384;
    n = nt * 16 + (lane & 15);
    kbase = ks * 32 + ((lane >> 4) * 8);
    dst = allfrag + (size_t)s * FRAG_S;
    dstidx = nt * 4 + ks;
  } else if (blk < 272) {
    const int s = (blk - 192) / 40, r = (blk - 192) - s * 40;
    const int snt = r >> 2, ks = r & 3;
    B = Wf + (size_t)s * 32768; ldb = 256;
    n = snt * 16 + (lane & 15);
    kbase = ks * 32 + ((lane >> 4) * 8);
    dst = allfrag + (size_t)s * FRAG_S;
    dstidx = (24 + snt) * 4 + ks;
  } else if (blk < 368) {
    const int r = blk - 272;
    const int nt = r / 12, ks = r - nt * 12;
    B = trans_w; ldb = 128;
    n = nt * 16 + (lane & 15);
    kbase = ks * 32 + ((lane >> 4) * 8);
    dst = transfrag;
    dstidx = nt * 12 + ks;
  } else {
    const int s = blk - 368;
    for (int c = lane; c < 544; c += 64) {
      float v;
      if (c < 384) {
        v = qkv_b[s * 384 + c];
      } else {
        const float* bk = qkv_b + (size_t)s * 384 + 128;
        const float* T  = Tt + (size_t)s * 128 * 256 + (c - 384);
        float a = 0.f;
        #pragma unroll 4
        for (int e = 0; e < 128; e++) a += bk[e] * T[(size_t)e * 256];
        v = a;
      }
      bc[s * 544 + c] = v;
    }
    return;
  }
  unsigned v[4];
  #pragma unroll
  for (int h = 0; h < 4; h++) {
    const float x0 = B[(size_t)(kbase + 2 * h) * ldb + n];
    const float x1 = B[(size_t)(kbase + 2 * h + 1) * ldb + n];
    v[h] = f2bf(x0) | ((unsigned)f2bf(x1) << 16);
  }
  uint4 o = {v[0], v[1], v[2], v[3]};
  *(uint4*)(dst + ((size_t)dstidx * 64 + lane) * 8) = o;
}

// ---------------------------------------------------------------------------
// MEGA: one block (8 waves, 512 threads) per voxel; whole network per voxel.
// qk_s row (stride 424): q/f2 0:128 | k,then P 128:256 | dk 256:416.
// feats_s holds x0, then f1 after layer-0 PV (trans chunk0 consumed x0 from
// the avu regs before the overwrite). red/wmax/pooled alias sc_s.
// ---------------------------------------------------------------------------
__global__ __launch_bounds__(512, 2) void mega(
    const float* __restrict__ inputs,
    const float* __restrict__ coords,
    const int*   __restrict__ groups,
    const unsigned short* __restrict__ allfrag,   // 2 x FRAG_S
    const float* __restrict__ bc,                 // 2 x 544
    const unsigned short* __restrict__ transfrag, // 8 nt x 12 ks
    const float* __restrict__ trans_b, const float* __restrict__ ln_g,
    const float* __restrict__ ln_b,
    float* __restrict__ out_all)
{
  __shared__ __align__(16) unsigned short feats_s[32][136];  // x0, then f1
  __shared__ __align__(16) unsigned short qk_s[32][424];     // q|k/P|dk; f2->q
  __shared__ __align__(16) unsigned short vT_s[128][40];     // V^T [f][j]
  __shared__ __align__(16) float sc_s[32 * 33];
  __shared__ float cs[32][4];
  // aliases into sc_s (scores dead after the last softmax):
  float (*red_s)[2][16][2] = (float (*)[2][16][2])sc_s;      // 2048 B
  float (*wmax_s)[128]     = (float (*)[128])(sc_s + 512);   // 1024 B
  float* pooled_s = sc_s;                                    // 512 B

  const int t   = threadIdx.x;
  const int bid = blockIdx.x;
  const int b   = bid >> 9;
  const int g   = bid & 511;
  const int wv = t >> 6, lane = t & 63, quad = lane >> 4, col = lane & 15;

  // ---- stage feats (gather + fp32->bf16): 16 thr/row, 8 elems each ----
  {
    const int p = t >> 4, sg = t & 15;
    const int pid = groups[(b << 14) + g * KP + p];
    const float* src = inputs + ((size_t)(b << 14) + (size_t)pid) * D_ + sg * 8;
    float4 a0 = *(const float4*)(src);
    float4 a1 = *(const float4*)(src + 4);
    uint4 o0;
    o0.x = f2bf(a0.x) | ((unsigned)f2bf(a0.y) << 16);
    o0.y = f2bf(a0.z) | ((unsigned)f2bf(a0.w) << 16);
    o0.z = f2bf(a1.x) | ((unsigned)f2bf(a1.y) << 16);
    o0.w = f2bf(a1.z) | ((unsigned)f2bf(a1.w) << 16);
    *(uint4*)&feats_s[p][sg * 8] = o0;
  }
  if (t < 32) {
    const int pid = groups[(b << 14) + g * KP + t];
    const float* cp = coords + ((size_t)(b << 14) + (size_t)pid) * 3;
    cs[t][0] = cp[0]; cs[t][1] = cp[1]; cs[t][2] = cp[2];
  }
  __syncthreads();

  // ---- phase-A tile ranges: frag read once per block ----
  const int startsA[8] = {0, 5, 10, 14, 18, 22, 26, 30};
  const int cntsA[8]   = {5, 5, 4, 4, 4, 4, 4, 4};
  const int start = startsA[wv];
  const int cnt   = cntsA[wv];

  // persistent trans accumulators: wave wv owns output cols wv*16..wv*16+15
  f32x4 tacc[2];
  tacc[0] = (f32x4){0.f, 0.f, 0.f, 0.f};
  tacc[1] = (f32x4){0.f, 0.f, 0.f, 0.f};
  const uint4* tf = (const uint4*)transfrag + lane;

  for (int layer = 0; layer < 2; layer++) {
    const uint4* fr = (const uint4*)(allfrag + (size_t)layer * FRAG_S) + lane;
    const float* bcl = bc + layer * 544;

    // A-frags for BOTH row halves; layer 0: x0, layer 1: f1 (same buffer)
    uint4 avu[2][4];
    #pragma unroll
    for (int ks = 0; ks < 4; ks++) {
      avu[0][ks] = *(const uint4*)&feats_s[col][ks * 32 + quad * 8];
      avu[1][ks] = *(const uint4*)&feats_s[16 + col][ks * 32 + quad * 8];
    }

    // Phase A with depth-1 prefetch of next tile's B-frags
    uint4 bvc[4];
    #pragma unroll
    for (int ks = 0; ks < 4; ks++) bvc[ks] = fr[(start * 4 + ks) * 64];

    for (int u = 0; u < cnt; u++) {
      const int ntn = start + ((u + 1 < cnt) ? (u + 1) : u);
      uint4 bvn[4];
      #pragma unroll
      for (int ks = 0; ks < 4; ks++) bvn[ks] = fr[(ntn * 4 + ks) * 64];

      f32x4 a0 = (f32x4){0.f, 0.f, 0.f, 0.f};
      f32x4 a1 = (f32x4){0.f, 0.f, 0.f, 0.f};
      #pragma unroll
      for (int ks = 0; ks < 4; ks++) {
        short8 bv = as_short8(bvc[ks]);
        a0 = __builtin_amdgcn_mfma_f32_16x16x32_bf16(as_short8(avu[0][ks]), bv, a0, 0, 0, 0);
        a1 = __builtin_amdgcn_mfma_f32_16x16x32_bf16(as_short8(avu[1][ks]), bv, a1, 0, 0, 0);
      }
      const int nt = start + u;
      const int cc = nt * 16 + col;
      const float bsv = bcl[cc];
      if (cc >= 256 && cc < 384) {          // V tile -> vT_s[f][j], b64 x2
        const unsigned lo0 = f2bf(a0[0] + bsv) | ((unsigned)f2bf(a0[1] + bsv) << 16);
        const unsigned hi0 = f2bf(a0[2] + bsv) | ((unsigned)f2bf(a0[3] + bsv) << 16);
        uint2 w0 = {lo0, hi0};
        *(uint2*)&vT_s[cc - 256][quad * 4] = w0;
        const unsigned lo1 = f2bf(a1[0] + bsv) | ((unsigned)f2bf(a1[1] + bsv) << 16);
        const unsigned hi1 = f2bf(a1[2] + bsv) | ((unsigned)f2bf(a1[3] + bsv) << 16);
        uint2 w1 = {lo1, hi1};
        *(uint2*)&vT_s[cc - 256][16 + quad * 4] = w1;
      } else {
        const int ccol = (cc < 256) ? cc : cc - 128;   // dk -> 256..415
        #pragma unroll
        for (int reg = 0; reg < 4; reg++) {
          qk_s[quad * 4 + reg][ccol]      = f2bf(a0[reg] + bsv);
          qk_s[16 + quad * 4 + reg][ccol] = f2bf(a1[reg] + bsv);
        }
      }
      #pragma unroll
      for (int ks = 0; ks < 4; ks++) bvc[ks] = bvn[ks];
    }
    // prefetch this layer's trans-chunk B-frags; the barrier's vmcnt drain
    // absorbs the latency.
    uint4 tgv[4];
    #pragma unroll
    for (int ks = 0; ks < 4; ks++) tgv[ks] = tf[(wv * 12 + layer * 4 + ks) * 64];
    __syncthreads();

    // scores via MFMA from LDS frags (waves 0..3)
    if (wv < 4) {
      const int ihalf = wv >> 1, jhalf = wv & 1;
      f32x4 sacc = {0.f, 0.f, 0.f, 0.f};
      #pragma unroll
      for (int ks = 0; ks < 4; ks++) {
        short8 qv = as_short8(*(const uint4*)&qk_s[ihalf * 16 + col][ks * 32 + quad * 8]);
        short8 kv = as_short8(*(const uint4*)&qk_s[jhalf * 16 + col][128 + ks * 32 + quad * 8]);
        sacc = __builtin_amdgcn_mfma_f32_16x16x32_bf16(qv, kv, sacc, 0, 0, 0);
      }
      const int j = jhalf * 16 + col;
      const float cjx = cs[j][0], cjy = cs[j][1], cjz = cs[j][2];
      #pragma unroll
      for (int reg = 0; reg < 4; reg++) {
        const int i = ihalf * 16 + quad * 4 + reg;
        const float dx = cs[i][0] - cjx;
        const float dy = cs[i][1] - cjy;
        const float dz = cs[i][2] - cjz;
        int ix = (int)floorf((dx + VSF) / QSF);
        int iy = (int)floorf((dy + VSF) / QSF);
        int iz = (int)floorf((dz + VSF) / QSF);
        ix = ix < 0 ? 0 : (ix > 49 ? 49 : ix);
        iy = iy < 0 ? 0 : (iy > 49 ? 49 : iy);
        iz = iz < 0 ? 0 : (iz > 49 ? 49 : iz);
        const unsigned short* dki = &qk_s[i][256];
        const float biasv = bu(dki[ix]) + bu(dki[50 + iy]) + bu(dki[100 + iz]);
        sc_s[i * 33 + j] = (sacc[reg] + biasv) * SCALE;
      }
    }
    // trans chunk (k-block = this layer's A operand), reusing live avu regs.
    // Waves 4..7 run this in their scores-idle window.
    #pragma unroll
    for (int ks = 0; ks < 4; ks++) {
      short8 bv = as_short8(tgv[ks]);
      tacc[0] = __builtin_amdgcn_mfma_f32_16x16x32_bf16(as_short8(avu[0][ks]), bv, tacc[0], 0, 0, 0);
      tacc[1] = __builtin_amdgcn_mfma_f32_16x16x32_bf16(as_short8(avu[1][ks]), bv, tacc[1], 0, 0, 0);
    }
    __syncthreads();

    // softmax: 8 threads per row (t<256); emit bf16 P over dead k cols 128..159
    if (t < 256) {
      const int p = t >> 3, sg = t & 7;
      float vals[4];
      float lm = -1e30f;
      #pragma unroll
      for (int u = 0; u < 4; u++) {
        vals[u] = sc_s[p * 33 + sg + u * 8];
        lm = fmaxf(lm, vals[u]);
      }
      lm = fmaxf(lm, __shfl_xor(lm, 1));
      lm = fmaxf(lm, __shfl_xor(lm, 2));
      lm = fmaxf(lm, __shfl_xor(lm, 4));
      float ls = 0.f;
      #pragma unroll
      for (int u = 0; u < 4; u++) { vals[u] = __expf(vals[u] - lm); ls += vals[u]; }
      ls += __shfl_xor(ls, 1);
      ls += __shfl_xor(ls, 2);
      ls += __shfl_xor(ls, 4);
      const float inv = 1.f / ls;
      #pragma unroll
      for (int u = 0; u < 4; u++)
        qk_s[p][128 + sg + u * 8] = f2bf(vals[u] * inv);
    }
    __syncthreads();

    // PV via MFMA: wave wv does mt=wv&1, ftiles (wv>>1)*2 + {0,1}.
    // layer 0 -> f1 overwrites feats_s; layer 1 -> f2 into qk_s cols 0..127.
    {
      const int mt = wv & 1, ftb = (wv >> 1) * 2;
      unsigned short* dst_base = (layer == 0) ? &feats_s[0][0] : &qk_s[0][0];
      const int dst_ld = (layer == 0) ? 136 : 424;
      short8 pv = as_short8(*(const uint4*)&qk_s[mt * 16 + col][128 + quad * 8]);
      #pragma unroll
      for (int u = 0; u < 2; u++) {
        const int ft = ftb + u;
        short8 vv = as_short8(*(const uint4*)&vT_s[ft * 16 + col][quad * 8]);
        f32x4 o = (f32x4){0.f, 0.f, 0.f, 0.f};
        o = __builtin_amdgcn_mfma_f32_16x16x32_bf16(pv, vv, o, 0, 0, 0);
        const int f = ft * 16 + col;
        #pragma unroll
        for (int reg = 0; reg < 4; reg++) {
          const int i = mt * 16 + quad * 4 + reg;
          dst_base[i * dst_ld + f] = f2bf(o[reg]);
        }
      }
    }
    __syncthreads();
  }

  // ---- trans GEMM tail: only the f2 chunk (ks 8..11) remains ----
  const int nt = wv;
  {
    uint4 gv[4];
    #pragma unroll
    for (int ks = 0; ks < 4; ks++) gv[ks] = tf[(nt * 12 + 8 + ks) * 64];
    #pragma unroll
    for (int ks = 0; ks < 4; ks++) {
      short8 bv = as_short8(gv[ks]);
      #pragma unroll
      for (int mt = 0; mt < 2; mt++) {
        short8 av = as_short8(*(const uint4*)&qk_s[mt * 16 + col][ks * 32 + quad * 8]);
        tacc[mt] = __builtin_amdgcn_mfma_f32_16x16x32_bf16(av, bv, tacc[mt], 0, 0, 0);
      }
    }
  }
  // bias + LN partial stats (16 cols per wave, both mtiles)
  const int c = nt * 16 + col;
  const float bsv = trans_b[c], gg = ln_g[c], lb = ln_b[c];
  float s[2][4], ssq[2][4];
  #pragma unroll
  for (int mt = 0; mt < 2; mt++)
    #pragma unroll
    for (int reg = 0; reg < 4; reg++) {
      const float v = tacc[mt][reg] + bsv;
      tacc[mt][reg] = v;
      s[mt][reg] = v; ssq[mt][reg] = v * v;
    }
  #pragma unroll
  for (int mk = 1; mk <= 8; mk <<= 1) {
    #pragma unroll
    for (int mt = 0; mt < 2; mt++)
      #pragma unroll
      for (int reg = 0; reg < 4; reg++) {
        s[mt][reg]   += __shfl_xor(s[mt][reg],   mk);
        ssq[mt][reg] += __shfl_xor(ssq[mt][reg], mk);
      }
  }
  if (col == 0) {
    #pragma unroll
    for (int mt = 0; mt < 2; mt++)
      #pragma unroll
      for (int reg = 0; reg < 4; reg++) {
        red_s[wv][mt][quad * 4 + reg][0] = s[mt][reg];
        red_s[wv][mt][quad * 4 + reg][1] = ssq[mt][reg];
      }
  }
  __syncthreads();
  float mu[2][4], rstd[2][4];
  #pragma unroll
  for (int mt = 0; mt < 2; mt++)
    #pragma unroll
    for (int reg = 0; reg < 4; reg++) {
      float st = 0.f, sst = 0.f;
      #pragma unroll
      for (int w = 0; w < 8; w++) {
        st  += red_s[w][mt][quad * 4 + reg][0];
        sst += red_s[w][mt][quad * 4 + reg][1];
      }
      mu[mt][reg] = st * (1.f / 128.f);
      const float var = sst * (1.f / 128.f) - mu[mt][reg] * mu[mt][reg];
      rstd[mt][reg] = rsqrtf(var + 1e-5f);
    }
  // LN + ReLU + column max over 16 rows of each mtile
  float cm[2];
  #pragma unroll
  for (int mt = 0; mt < 2; mt++) {
    float mx = 0.f;   // ReLU floor
    #pragma unroll
    for (int reg = 0; reg < 4; reg++) {
      float v = (tacc[mt][reg] - mu[mt][reg]) * rstd[mt][reg] * gg + lb;
      v = fmaxf(v, 0.f);
      mx = fmaxf(mx, v);
    }
    cm[mt] = mx;
  }
  #pragma unroll
  for (int mt = 0; mt < 2; mt++) {
    cm[mt] = fmaxf(cm[mt], __shfl_xor(cm[mt], 16));
    cm[mt] = fmaxf(cm[mt], __shfl_xor(cm[mt], 32));
  }
  __syncthreads();   // all red_s reads done (wmax aliases sc_s too)
  if (quad == 0) {
    #pragma unroll
    for (int mt = 0; mt < 2; mt++)
      wmax_s[mt][c] = cm[mt];
  }
  __syncthreads();

  // pooled = max over both row halves; grid-reordered out write
  if (t < 128) {
    const int cc = t;
    const float mx = fmaxf(wmax_s[0][cc], wmax_s[1][cc]);
    pooled_s[cc] = mx;                 // overwrites dead red_s region
    const int mm = g >> 6, nn = (g >> 3) & 7, tt2 = g & 7;
    const int opos = tt2 * 64 + nn * 8 + mm;
    out_all[((size_t)b * G_ + opos) * D_ + cc] = mx;
  }
  __syncthreads();

  // scatter pooled to every point (for_ret); 256 threads, 16 floats each
  if (t < 256) {
    const int p = t >> 3, sg = t & 7;
    const int pid = groups[(b << 14) + g * KP + p];
    float* dst = out_all + (size_t)BB * G_ * D_
               + ((size_t)(b << 14) + (size_t)pid) * D_ + sg * 16;
    #pragma unroll
    for (int u = 0; u < 4; u++)
      *(float4*)(dst + u * 4) = *(const float4*)&pooled_s[sg * 16 + u * 4];
  }
}

// ---------------------------------------------------------------------------
extern "C" void kernel_launch(void* const* d_in, const int* in_sizes, int n_in,
                              void* d_out, int out_size, void* d_ws, size_t ws_size,
                              hipStream_t stream) {
  const float* inputs  = (const float*)d_in[0];
  const float* coords  = (const float*)d_in[1];
  const float* qkv_w   = (const float*)d_in[2];   // [2,128,384]
  const float* qkv_b   = (const float*)d_in[3];   // [2,384]
  const float* tbl_x   = (const float*)d_in[4];   // [2,3,50,128]
  const float* tbl_y   = (const float*)d_in[5];
  const float* tbl_z   = (const float*)d_in[6];
  const float* trans_w = (const float*)d_in[7];   // [384,128]
  const float* trans_b = (const float*)d_in[8];
  const float* ln_g    = (const float*)d_in[9];
  const float* ln_b    = (const float*)d_in[10];
  const int*   groups  = (const int*)d_in[11];    // [2,512,32] flat

  float* out = (float*)d_out;
  unsigned short* allfrag   = (unsigned short*)d_ws;       // 2*FRAG_S
  unsigned short* transfrag = allfrag + 2 * FRAG_S;        // 96*512
  float* Tt  = (float*)(transfrag + 96 * 512);             // 2*128*256 f32
  float* Wf  = Tt + (size_t)2 * 128 * 256;                 // 2*128*256 f32
  float* bc  = Wf + (size_t)2 * 128 * 256;                 // 2*544 f32

  // ---- prep (weights only) ----
  prep_tt<<<256, 256, 0, stream>>>(tbl_x, tbl_y, tbl_z, Tt);
  wf_gemm<<<dim3(2, 2, 2), 256, 0, stream>>>(qkv_w, Tt, Wf);
  pack2<<<370, 64, 0, stream>>>(qkv_w, Wf, trans_w, qkv_b, Tt,
                                allfrag, transfrag, bc);

  // ---- whole network, one kernel ----
  mega<<<BB * G_, 512, 0, stream>>>(inputs, coords, groups, allfrag, bc,
                                    transfrag, trans_b, ln_g, ln_b, out);
}

// Round 2
// 139.849 us; speedup vs baseline: 1.1833x; 1.1833x over previous
//
#include <hip/hip_runtime.h>
#include <cstddef>

// Voxel encoder: B=2, N=16384, G=512 voxels x K=32 pts, d=128, S=2 layers.
// Round 15: prep-chain fusion. r14's LDS diet (64000->51200B) changed NOTHING
// in mega (45.5us, Occ 33%, MfmaUtil 10.5) -> mega is critical-path-bound,
// not LDS-occupancy-bound. But total=165us vs mega=45.5us: dispatch list
// shows wf_gemm ran 8 blocks x 256 thr (97% of chip idle) + prep_tt + pack2
// as 3 serialized launches (~75us incl. gaps). This round: ONE prep_all
// kernel (370 x 64); the 80 Wf-frag blocks compute their Wf slice on the fly
// (LDS-staged Wk rows + table cols, same e-ascending fp32 order -> bitwise
// identical), bc blocks read tables directly. Tt/Wf buffers gone. mega is
// byte-identical to r14 for clean attribution.
// RULE (r8/r10): never force min-waves>2.

#define D_   128
#define VSF  0.25f
#define QSF  0.01f
#define LQ   50
#define G_   512
#define KP   32
#define BB   2
#define NP   16384
#define MT   32768
#define SCALE 0.08838834764831845f   // 1/sqrt(128)
#define NT_ALL 34           // 24 qkv tiles + 10 dk tiles (cols 0..543)
#define FRAG_S (NT_ALL * 4 * 64 * 8)   // ushorts per layer frag buffer

using short8 = __attribute__((ext_vector_type(8))) short;
using f32x4  = __attribute__((ext_vector_type(4))) float;

__device__ inline unsigned short f2bf(float x) {
  unsigned u = __builtin_bit_cast(unsigned, x);
  u += 0x7fffu + ((u >> 16) & 1u);      // round-to-nearest-even
  return (unsigned short)(u >> 16);
}
__device__ inline float bu(unsigned short h) {
  return __builtin_bit_cast(float, (unsigned)h << 16);
}
__device__ inline short8 as_short8(uint4 v) {
  union { uint4 u; short8 s; } x; x.u = v; return x.s;
}

// ---------------------------------------------------------------------------
// prep_all: all weight preprocessing in ONE launch. 370 blocks x 64 threads.
//   blk   0..191: qkv-weight frags (direct from qkv_w)
//   blk 192..271: Wf frags, Wf = Wk @ T computed on the fly (LDS-staged)
//   blk 272..367: trans-weight frags (direct from trans_w)
//   blk 368..369: combined bias bc (qkv_b | bk @ T, direct from tables)
// ---------------------------------------------------------------------------
__global__ __launch_bounds__(64) void prep_all(
    const float* __restrict__ qkv_w, const float* __restrict__ trans_w,
    const float* __restrict__ qkv_b,
    const float* __restrict__ tbl_x, const float* __restrict__ tbl_y,
    const float* __restrict__ tbl_z,
    unsigned short* __restrict__ allfrag,
    unsigned short* __restrict__ transfrag,
    float* __restrict__ bc)
{
  __shared__ __align__(16) float As[32][132];   // Wk rows   (Wf branch only)
  __shared__ __align__(16) float Ts[16][132];   // T columns (Wf branch only)

  const int blk  = blockIdx.x;
  const int lane = threadIdx.x;

  if (blk >= 192 && blk < 272) {
    // ---- Wf frag blocks: compute Wf[m][c] = sum_e Wk[m][e] * T[e][c] ----
    const int s = (blk - 192) / 40, r = (blk - 192) - s * 40;
    const int snt = r >> 2, ks = r & 3;
    // stage Wk rows m = ks*32 .. ks*32+31 (e contiguous in qkv_w row)
    const float* Abase = qkv_w + (size_t)s * 128 * 384 + 128;
    for (int i = lane; i < 32 * 32; i += 64) {
      const int m = i >> 5, q = i & 31;
      float4 v = *(const float4*)(Abase + (size_t)(ks * 32 + m) * 384 + q * 4);
      *(float4*)&As[m][q * 4] = v;
    }
    // stage T columns c = snt*16 .. snt*16+15 (e contiguous in table row)
    for (int i = lane; i < 16 * 32; i += 64) {
      const int cl = i >> 5, q = i & 31;
      const int c = snt * 16 + cl;
      float4 v = {0.f, 0.f, 0.f, 0.f};
      if (c < 150) {
        const int axis = c / 50, l = c - axis * 50;
        const float* tb = (axis == 0 ? tbl_x : (axis == 1 ? tbl_y : tbl_z));
        v = *(const float4*)(tb + (((size_t)s * 3 + 1) * LQ + l) * D_ + q * 4);
      }
      *(float4*)&Ts[cl][q * 4] = v;
    }
    __syncthreads();
    const int cl = lane & 15, mb = (lane >> 4) * 8;
    float acc[8];
    #pragma unroll
    for (int m = 0; m < 8; m++) acc[m] = 0.f;
    for (int e = 0; e < 128; e += 4) {
      float4 tv = *(const float4*)&Ts[cl][e];
      #pragma unroll
      for (int m = 0; m < 8; m++) {
        float4 av = *(const float4*)&As[mb + m][e];
        // sequential adds: keep e-ascending fp32 order (bitwise == old path)
        acc[m] += av.x * tv.x;
        acc[m] += av.y * tv.y;
        acc[m] += av.z * tv.z;
        acc[m] += av.w * tv.w;
      }
    }
    unsigned v[4];
    #pragma unroll
    for (int h = 0; h < 4; h++)
      v[h] = f2bf(acc[2 * h]) | ((unsigned)f2bf(acc[2 * h + 1]) << 16);
    uint4 o = {v[0], v[1], v[2], v[3]};
    unsigned short* dst = allfrag + (size_t)s * FRAG_S;
    const int dstidx = (24 + snt) * 4 + ks;
    *(uint4*)(dst + ((size_t)dstidx * 64 + lane) * 8) = o;
    return;
  }

  if (blk >= 368) {
    // ---- bc: [0,384) qkv_b copy; [384,544) = bk @ T from tables ----
    const int s = blk - 368;
    for (int c = lane; c < 544; c += 64) {
      float v;
      if (c < 384) {
        v = qkv_b[s * 384 + c];
      } else {
        const int cc = c - 384;
        float a = 0.f;
        if (cc < 150) {
          const int axis = cc / 50, l = cc - axis * 50;
          const float* tb = (axis == 0 ? tbl_x : (axis == 1 ? tbl_y : tbl_z));
          const float* tr = tb + (((size_t)s * 3 + 1) * LQ + l) * D_;
          const float* bk = qkv_b + (size_t)s * 384 + 128;
          #pragma unroll 4
          for (int e = 0; e < 128; e++) a += bk[e] * tr[e];
        }
        v = a;
      }
      bc[s * 544 + c] = v;
    }
    return;
  }

  // ---- direct frag packing (qkv / trans weights) ----
  const float* B; int ldb, dstidx; unsigned short* dst; int kbase, n;
  if (blk < 192) {
    const int s = blk / 96, r = blk - s * 96;
    const int nt = r >> 2, ks = r & 3;
    B = qkv_w + (size_t)s * 128 * 384; ldb = 384;
    n = nt * 16 + (lane & 15);
    kbase = ks * 32 + ((lane >> 4) * 8);
    dst = allfrag + (size_t)s * FRAG_S;
    dstidx = nt * 4 + ks;
  } else {
    const int r = blk - 272;
    const int nt = r / 12, ks = r - nt * 12;
    B = trans_w; ldb = 128;
    n = nt * 16 + (lane & 15);
    kbase = ks * 32 + ((lane >> 4) * 8);
    dst = transfrag;
    dstidx = nt * 12 + ks;
  }
  unsigned v[4];
  #pragma unroll
  for (int h = 0; h < 4; h++) {
    const float x0 = B[(size_t)(kbase + 2 * h) * ldb + n];
    const float x1 = B[(size_t)(kbase + 2 * h + 1) * ldb + n];
    v[h] = f2bf(x0) | ((unsigned)f2bf(x1) << 16);
  }
  uint4 o = {v[0], v[1], v[2], v[3]};
  *(uint4*)(dst + ((size_t)dstidx * 64 + lane) * 8) = o;
}

// ---------------------------------------------------------------------------
// MEGA: one block (8 waves, 512 threads) per voxel; whole network per voxel.
// qk_s row (stride 424): q/f2 0:128 | k,then P 128:256 | dk 256:416.
// feats_s holds x0, then f1 after layer-0 PV (trans chunk0 consumed x0 from
// the avu regs before the overwrite). red/wmax/pooled alias sc_s.
// (byte-identical to r14)
// ---------------------------------------------------------------------------
__global__ __launch_bounds__(512, 2) void mega(
    const float* __restrict__ inputs,
    const float* __restrict__ coords,
    const int*   __restrict__ groups,
    const unsigned short* __restrict__ allfrag,   // 2 x FRAG_S
    const float* __restrict__ bc,                 // 2 x 544
    const unsigned short* __restrict__ transfrag, // 8 nt x 12 ks
    const float* __restrict__ trans_b, const float* __restrict__ ln_g,
    const float* __restrict__ ln_b,
    float* __restrict__ out_all)
{
  __shared__ __align__(16) unsigned short feats_s[32][136];  // x0, then f1
  __shared__ __align__(16) unsigned short qk_s[32][424];     // q|k/P|dk; f2->q
  __shared__ __align__(16) unsigned short vT_s[128][40];     // V^T [f][j]
  __shared__ __align__(16) float sc_s[32 * 33];
  __shared__ float cs[32][4];
  // aliases into sc_s (scores dead after the last softmax):
  float (*red_s)[2][16][2] = (float (*)[2][16][2])sc_s;      // 2048 B
  float (*wmax_s)[128]     = (float (*)[128])(sc_s + 512);   // 1024 B
  float* pooled_s = sc_s;                                    // 512 B

  const int t   = threadIdx.x;
  const int bid = blockIdx.x;
  const int b   = bid >> 9;
  const int g   = bid & 511;
  const int wv = t >> 6, lane = t & 63, quad = lane >> 4, col = lane & 15;

  // ---- stage feats (gather + fp32->bf16): 16 thr/row, 8 elems each ----
  {
    const int p = t >> 4, sg = t & 15;
    const int pid = groups[(b << 14) + g * KP + p];
    const float* src = inputs + ((size_t)(b << 14) + (size_t)pid) * D_ + sg * 8;
    float4 a0 = *(const float4*)(src);
    float4 a1 = *(const float4*)(src + 4);
    uint4 o0;
    o0.x = f2bf(a0.x) | ((unsigned)f2bf(a0.y) << 16);
    o0.y = f2bf(a0.z) | ((unsigned)f2bf(a0.w) << 16);
    o0.z = f2bf(a1.x) | ((unsigned)f2bf(a1.y) << 16);
    o0.w = f2bf(a1.z) | ((unsigned)f2bf(a1.w) << 16);
    *(uint4*)&feats_s[p][sg * 8] = o0;
  }
  if (t < 32) {
    const int pid = groups[(b << 14) + g * KP + t];
    const float* cp = coords + ((size_t)(b << 14) + (size_t)pid) * 3;
    cs[t][0] = cp[0]; cs[t][1] = cp[1]; cs[t][2] = cp[2];
  }
  __syncthreads();

  // ---- phase-A tile ranges: frag read once per block ----
  const int startsA[8] = {0, 5, 10, 14, 18, 22, 26, 30};
  const int cntsA[8]   = {5, 5, 4, 4, 4, 4, 4, 4};
  const int start = startsA[wv];
  const int cnt   = cntsA[wv];

  // persistent trans accumulators: wave wv owns output cols wv*16..wv*16+15
  f32x4 tacc[2];
  tacc[0] = (f32x4){0.f, 0.f, 0.f, 0.f};
  tacc[1] = (f32x4){0.f, 0.f, 0.f, 0.f};
  const uint4* tf = (const uint4*)transfrag + lane;

  for (int layer = 0; layer < 2; layer++) {
    const uint4* fr = (const uint4*)(allfrag + (size_t)layer * FRAG_S) + lane;
    const float* bcl = bc + layer * 544;

    // A-frags for BOTH row halves; layer 0: x0, layer 1: f1 (same buffer)
    uint4 avu[2][4];
    #pragma unroll
    for (int ks = 0; ks < 4; ks++) {
      avu[0][ks] = *(const uint4*)&feats_s[col][ks * 32 + quad * 8];
      avu[1][ks] = *(const uint4*)&feats_s[16 + col][ks * 32 + quad * 8];
    }

    // Phase A with depth-1 prefetch of next tile's B-frags
    uint4 bvc[4];
    #pragma unroll
    for (int ks = 0; ks < 4; ks++) bvc[ks] = fr[(start * 4 + ks) * 64];

    for (int u = 0; u < cnt; u++) {
      const int ntn = start + ((u + 1 < cnt) ? (u + 1) : u);
      uint4 bvn[4];
      #pragma unroll
      for (int ks = 0; ks < 4; ks++) bvn[ks] = fr[(ntn * 4 + ks) * 64];

      f32x4 a0 = (f32x4){0.f, 0.f, 0.f, 0.f};
      f32x4 a1 = (f32x4){0.f, 0.f, 0.f, 0.f};
      #pragma unroll
      for (int ks = 0; ks < 4; ks++) {
        short8 bv = as_short8(bvc[ks]);
        a0 = __builtin_amdgcn_mfma_f32_16x16x32_bf16(as_short8(avu[0][ks]), bv, a0, 0, 0, 0);
        a1 = __builtin_amdgcn_mfma_f32_16x16x32_bf16(as_short8(avu[1][ks]), bv, a1, 0, 0, 0);
      }
      const int nt = start + u;
      const int cc = nt * 16 + col;
      const float bsv = bcl[cc];
      if (cc >= 256 && cc < 384) {          // V tile -> vT_s[f][j], b64 x2
        const unsigned lo0 = f2bf(a0[0] + bsv) | ((unsigned)f2bf(a0[1] + bsv) << 16);
        const unsigned hi0 = f2bf(a0[2] + bsv) | ((unsigned)f2bf(a0[3] + bsv) << 16);
        uint2 w0 = {lo0, hi0};
        *(uint2*)&vT_s[cc - 256][quad * 4] = w0;
        const unsigned lo1 = f2bf(a1[0] + bsv) | ((unsigned)f2bf(a1[1] + bsv) << 16);
        const unsigned hi1 = f2bf(a1[2] + bsv) | ((unsigned)f2bf(a1[3] + bsv) << 16);
        uint2 w1 = {lo1, hi1};
        *(uint2*)&vT_s[cc - 256][16 + quad * 4] = w1;
      } else {
        const int ccol = (cc < 256) ? cc : cc - 128;   // dk -> 256..415
        #pragma unroll
        for (int reg = 0; reg < 4; reg++) {
          qk_s[quad * 4 + reg][ccol]      = f2bf(a0[reg] + bsv);
          qk_s[16 + quad * 4 + reg][ccol] = f2bf(a1[reg] + bsv);
        }
      }
      #pragma unroll
      for (int ks = 0; ks < 4; ks++) bvc[ks] = bvn[ks];
    }
    // prefetch this layer's trans-chunk B-frags; the barrier's vmcnt drain
    // absorbs the latency.
    uint4 tgv[4];
    #pragma unroll
    for (int ks = 0; ks < 4; ks++) tgv[ks] = tf[(wv * 12 + layer * 4 + ks) * 64];
    __syncthreads();

    // scores via MFMA from LDS frags (waves 0..3)
    if (wv < 4) {
      const int ihalf = wv >> 1, jhalf = wv & 1;
      f32x4 sacc = {0.f, 0.f, 0.f, 0.f};
      #pragma unroll
      for (int ks = 0; ks < 4; ks++) {
        short8 qv = as_short8(*(const uint4*)&qk_s[ihalf * 16 + col][ks * 32 + quad * 8]);
        short8 kv = as_short8(*(const uint4*)&qk_s[jhalf * 16 + col][128 + ks * 32 + quad * 8]);
        sacc = __builtin_amdgcn_mfma_f32_16x16x32_bf16(qv, kv, sacc, 0, 0, 0);
      }
      const int j = jhalf * 16 + col;
      const float cjx = cs[j][0], cjy = cs[j][1], cjz = cs[j][2];
      #pragma unroll
      for (int reg = 0; reg < 4; reg++) {
        const int i = ihalf * 16 + quad * 4 + reg;
        const float dx = cs[i][0] - cjx;
        const float dy = cs[i][1] - cjy;
        const float dz = cs[i][2] - cjz;
        int ix = (int)floorf((dx + VSF) / QSF);
        int iy = (int)floorf((dy + VSF) / QSF);
        int iz = (int)floorf((dz + VSF) / QSF);
        ix = ix < 0 ? 0 : (ix > 49 ? 49 : ix);
        iy = iy < 0 ? 0 : (iy > 49 ? 49 : iy);
        iz = iz < 0 ? 0 : (iz > 49 ? 49 : iz);
        const unsigned short* dki = &qk_s[i][256];
        const float biasv = bu(dki[ix]) + bu(dki[50 + iy]) + bu(dki[100 + iz]);
        sc_s[i * 33 + j] = (sacc[reg] + biasv) * SCALE;
      }
    }
    // trans chunk (k-block = this layer's A operand), reusing live avu regs.
    // Waves 4..7 run this in their scores-idle window.
    #pragma unroll
    for (int ks = 0; ks < 4; ks++) {
      short8 bv = as_short8(tgv[ks]);
      tacc[0] = __builtin_amdgcn_mfma_f32_16x16x32_bf16(as_short8(avu[0][ks]), bv, tacc[0], 0, 0, 0);
      tacc[1] = __builtin_amdgcn_mfma_f32_16x16x32_bf16(as_short8(avu[1][ks]), bv, tacc[1], 0, 0, 0);
    }
    __syncthreads();

    // softmax: 8 threads per row (t<256); emit bf16 P over dead k cols 128..159
    if (t < 256) {
      const int p = t >> 3, sg = t & 7;
      float vals[4];
      float lm = -1e30f;
      #pragma unroll
      for (int u = 0; u < 4; u++) {
        vals[u] = sc_s[p * 33 + sg + u * 8];
        lm = fmaxf(lm, vals[u]);
      }
      lm = fmaxf(lm, __shfl_xor(lm, 1));
      lm = fmaxf(lm, __shfl_xor(lm, 2));
      lm = fmaxf(lm, __shfl_xor(lm, 4));
      float ls = 0.f;
      #pragma unroll
      for (int u = 0; u < 4; u++) { vals[u] = __expf(vals[u] - lm); ls += vals[u]; }
      ls += __shfl_xor(ls, 1);
      ls += __shfl_xor(ls, 2);
      ls += __shfl_xor(ls, 4);
      const float inv = 1.f / ls;
      #pragma unroll
      for (int u = 0; u < 4; u++)
        qk_s[p][128 + sg + u * 8] = f2bf(vals[u] * inv);
    }
    __syncthreads();

    // PV via MFMA: wave wv does mt=wv&1, ftiles (wv>>1)*2 + {0,1}.
    // layer 0 -> f1 overwrites feats_s; layer 1 -> f2 into qk_s cols 0..127.
    {
      const int mt = wv & 1, ftb = (wv >> 1) * 2;
      unsigned short* dst_base = (layer == 0) ? &feats_s[0][0] : &qk_s[0][0];
      const int dst_ld = (layer == 0) ? 136 : 424;
      short8 pv = as_short8(*(const uint4*)&qk_s[mt * 16 + col][128 + quad * 8]);
      #pragma unroll
      for (int u = 0; u < 2; u++) {
        const int ft = ftb + u;
        short8 vv = as_short8(*(const uint4*)&vT_s[ft * 16 + col][quad * 8]);
        f32x4 o = (f32x4){0.f, 0.f, 0.f, 0.f};
        o = __builtin_amdgcn_mfma_f32_16x16x32_bf16(pv, vv, o, 0, 0, 0);
        const int f = ft * 16 + col;
        #pragma unroll
        for (int reg = 0; reg < 4; reg++) {
          const int i = mt * 16 + quad * 4 + reg;
          dst_base[i * dst_ld + f] = f2bf(o[reg]);
        }
      }
    }
    __syncthreads();
  }

  // ---- trans GEMM tail: only the f2 chunk (ks 8..11) remains ----
  const int nt = wv;
  {
    uint4 gv[4];
    #pragma unroll
    for (int ks = 0; ks < 4; ks++) gv[ks] = tf[(nt * 12 + 8 + ks) * 64];
    #pragma unroll
    for (int ks = 0; ks < 4; ks++) {
      short8 bv = as_short8(gv[ks]);
      #pragma unroll
      for (int mt = 0; mt < 2; mt++) {
        short8 av = as_short8(*(const uint4*)&qk_s[mt * 16 + col][ks * 32 + quad * 8]);
        tacc[mt] = __builtin_amdgcn_mfma_f32_16x16x32_bf16(av, bv, tacc[mt], 0, 0, 0);
      }
    }
  }
  // bias + LN partial stats (16 cols per wave, both mtiles)
  const int c = nt * 16 + col;
  const float bsv = trans_b[c], gg = ln_g[c], lb = ln_b[c];
  float s[2][4], ssq[2][4];
  #pragma unroll
  for (int mt = 0; mt < 2; mt++)
    #pragma unroll
    for (int reg = 0; reg < 4; reg++) {
      const float v = tacc[mt][reg] + bsv;
      tacc[mt][reg] = v;
      s[mt][reg] = v; ssq[mt][reg] = v * v;
    }
  #pragma unroll
  for (int mk = 1; mk <= 8; mk <<= 1) {
    #pragma unroll
    for (int mt = 0; mt < 2; mt++)
      #pragma unroll
      for (int reg = 0; reg < 4; reg++) {
        s[mt][reg]   += __shfl_xor(s[mt][reg],   mk);
        ssq[mt][reg] += __shfl_xor(ssq[mt][reg], mk);
      }
  }
  if (col == 0) {
    #pragma unroll
    for (int mt = 0; mt < 2; mt++)
      #pragma unroll
      for (int reg = 0; reg < 4; reg++) {
        red_s[wv][mt][quad * 4 + reg][0] = s[mt][reg];
        red_s[wv][mt][quad * 4 + reg][1] = ssq[mt][reg];
      }
  }
  __syncthreads();
  float mu[2][4], rstd[2][4];
  #pragma unroll
  for (int mt = 0; mt < 2; mt++)
    #pragma unroll
    for (int reg = 0; reg < 4; reg++) {
      float st = 0.f, sst = 0.f;
      #pragma unroll
      for (int w = 0; w < 8; w++) {
        st  += red_s[w][mt][quad * 4 + reg][0];
        sst += red_s[w][mt][quad * 4 + reg][1];
      }
      mu[mt][reg] = st * (1.f / 128.f);
      const float var = sst * (1.f / 128.f) - mu[mt][reg] * mu[mt][reg];
      rstd[mt][reg] = rsqrtf(var + 1e-5f);
    }
  // LN + ReLU + column max over 16 rows of each mtile
  float cm[2];
  #pragma unroll
  for (int mt = 0; mt < 2; mt++) {
    float mx = 0.f;   // ReLU floor
    #pragma unroll
    for (int reg = 0; reg < 4; reg++) {
      float v = (tacc[mt][reg] - mu[mt][reg]) * rstd[mt][reg] * gg + lb;
      v = fmaxf(v, 0.f);
      mx = fmaxf(mx, v);
    }
    cm[mt] = mx;
  }
  #pragma unroll
  for (int mt = 0; mt < 2; mt++) {
    cm[mt] = fmaxf(cm[mt], __shfl_xor(cm[mt], 16));
    cm[mt] = fmaxf(cm[mt], __shfl_xor(cm[mt], 32));
  }
  __syncthreads();   // all red_s reads done (wmax aliases sc_s too)
  if (quad == 0) {
    #pragma unroll
    for (int mt = 0; mt < 2; mt++)
      wmax_s[mt][c] = cm[mt];
  }
  __syncthreads();

  // pooled = max over both row halves; grid-reordered out write
  if (t < 128) {
    const int cc = t;
    const float mx = fmaxf(wmax_s[0][cc], wmax_s[1][cc]);
    pooled_s[cc] = mx;                 // overwrites dead red_s region
    const int mm = g >> 6, nn = (g >> 3) & 7, tt2 = g & 7;
    const int opos = tt2 * 64 + nn * 8 + mm;
    out_all[((size_t)b * G_ + opos) * D_ + cc] = mx;
  }
  __syncthreads();

  // scatter pooled to every point (for_ret); 256 threads, 16 floats each
  if (t < 256) {
    const int p = t >> 3, sg = t & 7;
    const int pid = groups[(b << 14) + g * KP + p];
    float* dst = out_all + (size_t)BB * G_ * D_
               + ((size_t)(b << 14) + (size_t)pid) * D_ + sg * 16;
    #pragma unroll
    for (int u = 0; u < 4; u++)
      *(float4*)(dst + u * 4) = *(const float4*)&pooled_s[sg * 16 + u * 4];
  }
}

// ---------------------------------------------------------------------------
extern "C" void kernel_launch(void* const* d_in, const int* in_sizes, int n_in,
                              void* d_out, int out_size, void* d_ws, size_t ws_size,
                              hipStream_t stream) {
  const float* inputs  = (const float*)d_in[0];
  const float* coords  = (const float*)d_in[1];
  const float* qkv_w   = (const float*)d_in[2];   // [2,128,384]
  const float* qkv_b   = (const float*)d_in[3];   // [2,384]
  const float* tbl_x   = (const float*)d_in[4];   // [2,3,50,128]
  const float* tbl_y   = (const float*)d_in[5];
  const float* tbl_z   = (const float*)d_in[6];
  const float* trans_w = (const float*)d_in[7];   // [384,128]
  const float* trans_b = (const float*)d_in[8];
  const float* ln_g    = (const float*)d_in[9];
  const float* ln_b    = (const float*)d_in[10];
  const int*   groups  = (const int*)d_in[11];    // [2,512,32] flat

  float* out = (float*)d_out;
  unsigned short* allfrag   = (unsigned short*)d_ws;       // 2*FRAG_S
  unsigned short* transfrag = allfrag + 2 * FRAG_S;        // 96*512
  float* bc  = (float*)(transfrag + 96 * 512);             // 2*544 f32

  // ---- ALL weight prep in one launch ----
  prep_all<<<370, 64, 0, stream>>>(qkv_w, trans_w, qkv_b,
                                   tbl_x, tbl_y, tbl_z,
                                   allfrag, transfrag, bc);

  // ---- whole network, one kernel ----
  mega<<<BB * G_, 512, 0, stream>>>(inputs, coords, groups, allfrag, bc,
                                    transfrag, trans_b, ln_g, ln_b, out);
}